// Round 4
// baseline (4495.924 us; speedup 1.0000x reference)
//
#include <hip/hip_runtime.h>

#define MAXNZ 96
#define NPAIR 48

typedef unsigned short u16;
typedef unsigned int u32;

// ---------------- prep: dense rec -> padded per-column sparse lists ----------------
// Layout (for coalesced loads in scan): wsv[dir][slot][col], wsi[dir][slot][col]
__global__ __launch_bounds__(512) void esn_prep(
    const float* __restrict__ rec_f, const float* __restrict__ rec_b,
    float* __restrict__ wsv, u16* __restrict__ wsi, int* __restrict__ wscnt)
{
    const int dir = blockIdx.x;
    const int u = threadIdx.x;
    const float* rec = dir ? rec_b : rec_f;
    int cnt = 0;
    for (int k = 0; k < 512; ++k) {
        float v = rec[k * 512 + u];          // coalesced across threads
        if (v != 0.0f && cnt < MAXNZ) {
            wsv[(dir * MAXNZ + cnt) * 512 + u] = v;
            wsi[(dir * MAXNZ + cnt) * 512 + u] = (u16)k;
            ++cnt;
        }
    }
    wscnt[dir * 512 + u] = cnt;
    for (int i = cnt; i < MAXNZ; ++i) {      // zero padding: val=0 makes idx irrelevant
        wsv[(dir * MAXNZ + i) * 512 + u] = 0.0f;
        wsi[(dir * MAXNZ + i) * 512 + u] = 0;
    }
}

// ---------------- projection GEMM: xin = x @ [kernel_f | kernel_b] + bias ----------
// M=65536 (B*T), K=512, N=1024. Written IN PLACE into d_out (same shape as output).
__global__ __launch_bounds__(256) void esn_proj(
    const float* __restrict__ x,
    const float* __restrict__ kf, const float* __restrict__ kb,
    const float* __restrict__ bf, const float* __restrict__ bb,
    float* __restrict__ out)
{
    __shared__ float As[16][132];   // A-tile transposed [k][m], pad to 132
    __shared__ float Bs[16][132];   // B-tile [k][n]
    const int tid = threadIdx.x;
    const int bm = blockIdx.x;      // 512 row blocks of 128
    const int bn = blockIdx.y;      // 8 col blocks of 128 (0-3 fwd, 4-7 bwd)
    const float* B    = (bn < 4) ? kf : kb;
    const float* bias = (bn < 4) ? bf : bb;
    const int colBase = (bn & 3) * 128;

    const int tm = tid >> 4;        // 0..15
    const int tn = tid & 15;        // 0..15

    float acc[8][8];
#pragma unroll
    for (int i = 0; i < 8; ++i)
#pragma unroll
        for (int j = 0; j < 8; ++j) acc[i][j] = 0.0f;

    const long aRow0 = (long)bm * 128;

    for (int k0 = 0; k0 < 512; k0 += 16) {
#pragma unroll
        for (int s = 0; s < 2; ++s) {
            int slot = tid + s * 256;
            int row = slot >> 2, c4 = slot & 3;
            float4 v = *(const float4*)&x[(aRow0 + row) * 512 + k0 + c4 * 4];
            As[c4 * 4 + 0][row] = v.x;
            As[c4 * 4 + 1][row] = v.y;
            As[c4 * 4 + 2][row] = v.z;
            As[c4 * 4 + 3][row] = v.w;
        }
#pragma unroll
        for (int s = 0; s < 2; ++s) {
            int slot = tid + s * 256;
            int kk = slot >> 5, c4 = slot & 31;
            *(float4*)&Bs[kk][c4 * 4] =
                *(const float4*)&B[(long)(k0 + kk) * 512 + colBase + c4 * 4];
        }
        __syncthreads();
#pragma unroll
        for (int k = 0; k < 16; ++k) {
            float a[8], b[8];
            *(float4*)&a[0] = *(const float4*)&As[k][tm * 4];
            *(float4*)&a[4] = *(const float4*)&As[k][64 + tm * 4];
            *(float4*)&b[0] = *(const float4*)&Bs[k][tn * 4];
            *(float4*)&b[4] = *(const float4*)&Bs[k][64 + tn * 4];
#pragma unroll
            for (int i = 0; i < 8; ++i)
#pragma unroll
                for (int j = 0; j < 8; ++j)
                    acc[i][j] += a[i] * b[j];
        }
        __syncthreads();
    }

#pragma unroll
    for (int jj = 0; jj < 2; ++jj) {
        float bv[4];
#pragma unroll
        for (int j = 0; j < 4; ++j) bv[j] = bias[colBase + jj * 64 + tn * 4 + j];
#pragma unroll
        for (int ii = 0; ii < 2; ++ii) {
#pragma unroll
            for (int i = 0; i < 4; ++i) {
                long r = aRow0 + ii * 64 + tm * 4 + i;
                float4 v;
                v.x = acc[ii * 4 + i][jj * 4 + 0] + bv[0];
                v.y = acc[ii * 4 + i][jj * 4 + 1] + bv[1];
                v.z = acc[ii * 4 + i][jj * 4 + 2] + bv[2];
                v.w = acc[ii * 4 + i][jj * 4 + 3] + bv[3];
                *(float4*)&out[r * 1024 + bn * 128 + jj * 64 + tn * 4] = v;
            }
        }
    }
}

// ---------------- scan: 64 independent recurrences, one workgroup each -------------
// Thread u owns column u: sparse column (vals/idx) in registers, h in LDS (dbuf).
// Reads u_t from io (the projection) and overwrites the same cell with the state.
__global__ __launch_bounds__(512) void esn_scan(
    const float* __restrict__ wsv, const u16* __restrict__ wsi,
    const int* __restrict__ wscnt, float* __restrict__ io)
{
    const int sid = blockIdx.x;
    const int dir = sid & 1;
    const int b = sid >> 1;
    const int u = threadIdx.x;

    __shared__ float h[2][512];

    float vals[MAXNZ];
    u32 poff[NPAIR];
    {
        const float* vb = wsv + (long)dir * MAXNZ * 512 + u;
        const u16* ib = wsi + (long)dir * MAXNZ * 512 + u;
#pragma unroll
        for (int i = 0; i < MAXNZ; ++i) vals[i] = vb[i * 512];
#pragma unroll
        for (int i = 0; i < NPAIR; ++i) {
            u32 o0 = ib[(2 * i) * 512];
            u32 o1 = ib[(2 * i + 1) * 512];
            poff[i] = o0 | (o1 << 16);
        }
    }
    int cmax = wscnt[dir * 512 + u];
#pragma unroll
    for (int d = 1; d < 64; d <<= 1) {
        int o = __shfl_xor(cmax, d, 64);
        cmax = cmax > o ? cmax : o;   // wave-uniform max count -> skip trailing blocks
    }

    h[0][u] = 0.0f;
    float hreg = 0.0f;
    __syncthreads();

    const long rowStep = dir ? -1024L : 1024L;
    long rowCur = ((long)b * 2048 + (dir ? 2047 : 0)) * 1024 + dir * 512 + u;
    float ucur = io[rowCur];
    long rowNext = rowCur + rowStep;

    for (int t = 0; t < 2048; ++t) {
        float unext = 0.0f;
        if (t < 2047) unext = io[rowNext];   // prefetch next u_t, hidden under gathers

        const float* hc = h[t & 1];
        float acc0 = ucur, acc1 = 0.0f;
#pragma unroll
        for (int blk = 0; blk < 6; ++blk) {
            if (blk * 16 < cmax) {
#pragma unroll
                for (int q = 0; q < 8; ++q) {
                    const int i = blk * 8 + q;
                    u32 p = poff[i];
                    acc0 += vals[2 * i]     * hc[p & 0xffffu];
                    acc1 += vals[2 * i + 1] * hc[p >> 16];
                }
            }
        }
        float acc = acc0 + acc1;
        // tanh(a) = 1 - 2/(exp2(a*2*log2e)+1); saturates correctly for |a| large
        float e = __builtin_exp2f(acc * 2.8853900817779268f);
        float r = __builtin_amdgcn_rcpf(e + 1.0f);
        float th = 1.0f - 2.0f * r;
        float hn = 0.1f * hreg + 0.9f * th;

        io[rowCur] = hn;                 // overwrite the u_t cell we consumed
        h[(t + 1) & 1][u] = hn;
        hreg = hn;
        __syncthreads();                 // one barrier per step (double-buffered h)

        ucur = unext;
        rowCur = rowNext;
        rowNext += rowStep;
    }
}

extern "C" void kernel_launch(void* const* d_in, const int* in_sizes, int n_in,
                              void* d_out, int out_size, void* d_ws, size_t ws_size,
                              hipStream_t stream) {
    const float* x  = (const float*)d_in[0];
    const float* kf = (const float*)d_in[1];
    const float* rf = (const float*)d_in[2];
    const float* bf = (const float*)d_in[3];
    const float* kb = (const float*)d_in[4];
    const float* rb = (const float*)d_in[5];
    const float* bb = (const float*)d_in[6];
    float* out = (float*)d_out;

    float* wsv = (float*)d_ws;                                        // 2*96*512 f32
    u16*   wsi = (u16*)((char*)d_ws + 2 * MAXNZ * 512 * 4);           // 2*96*512 u16
    int* wscnt = (int*)((char*)d_ws + 2 * MAXNZ * 512 * 6);           // 2*512 int

    esn_prep<<<2, 512, 0, stream>>>(rf, rb, wsv, wsi, wscnt);
    esn_proj<<<dim3(512, 8), 256, 0, stream>>>(x, kf, kb, bf, bb, out);
    esn_scan<<<64, 512, 0, stream>>>(wsv, wsi, wscnt, out);
}